// Round 1
// baseline (36083.344 us; speedup 1.0000x reference)
//
#include <hip/hip_runtime.h>
#include <math.h>

// Problem dims
#define B_SZ   32
#define T_SZ   512
#define I_DIM  256
#define H_DIM  1024
#define P_DIM  512
#define G4     4096   // 4*H
#define O_DIM  256

// Workspace layout (bytes). Total required: 168,558,592 (~161 MB).
//  RR    : 1024*4096*4 = 16MB   @ 0
//  RRt   : 4096*1024*4 = 16MB   @ 16777216
//  lwt   : 512*256*4   = 512KB  @ 33554432
//  c_st  : 32*1024*4   = 128KB  @ 34078720
//  h_seq : 513*32*1024*4 = 67,239,936 @ 34209792   (slot 0 = h_{-1} = 0)
//  xg_c  : 64*32*4096*4  = 33,554,432 @ 101449728  (rotating 64-step chunk)
//  hp_sq : 16384*512*4   = 33,554,432 @ 135004160

__device__ __forceinline__ float sigmf(float x) { return 1.0f / (1.0f + __expf(-x)); }
__device__ __forceinline__ float tanhfast(float x) { return 1.0f - 2.0f / (__expf(2.0f * x) + 1.0f); }

// ---------------------------------------------------------------------------
// Generic tiled f32 GEMM: C[M][N] = A[M][K] @ B[K][N] (+bias)
// BM=128, BN=64, BK=16, 256 threads, thread tile 8x4.
// MODE 0: RR = W_proj @ R                   (plain rows)
// MODE 1: xg chunk: A row r -> inputs[(r&31)*512 + t0 + (r>>5)] (row-major in i)
// MODE 2: hp_seq = h_seq[1..] @ W_proj      (plain rows)
// MODE 3: out: C row r=(t*32+b) -> d_out[b][t][:]
// ---------------------------------------------------------------------------
template<int MODE>
__global__ __launch_bounds__(256)
void gemm_f32(const float* __restrict__ A, const float* __restrict__ B,
              const float* __restrict__ bias, float* __restrict__ C,
              int M, int N, int K, int t0)
{
    __shared__ float As[16][136];   // [k][m], padded (136*4B % 16B == 0, banks spread)
    __shared__ float Bs[16][64];    // [k][n]
    const int row0 = blockIdx.y * 128;
    const int col0 = blockIdx.x * 64;
    const int tid = threadIdx.x;
    const int tx = tid & 15, ty = tid >> 4;

    float acc[8][4];
    #pragma unroll
    for (int r = 0; r < 8; r++)
        #pragma unroll
        for (int cc = 0; cc < 4; cc++) acc[r][cc] = 0.0f;

    for (int k0 = 0; k0 < K; k0 += 16) {
        // --- stage A tile (128 x 16) as float4 over k, store transposed ---
        #pragma unroll
        for (int e = 0; e < 2; e++) {
            int f4 = tid * 2 + e;          // 0..511
            int m  = f4 >> 2;              // 0..127
            int kq = f4 & 3;               // 0..3
            const float* ar;
            int r = row0 + m;
            if constexpr (MODE == 1)
                ar = A + (size_t)((r & 31) * 512 + t0 + (r >> 5)) * 256;
            else
                ar = A + (size_t)r * K;
            float4 v = *(const float4*)(ar + k0 + kq * 4);
            As[kq*4+0][m] = v.x; As[kq*4+1][m] = v.y;
            As[kq*4+2][m] = v.z; As[kq*4+3][m] = v.w;
        }
        // --- stage B tile (16 x 64) ---
        {
            int kk = tid >> 4, nq = tid & 15;
            float4 v = *(const float4*)(B + (size_t)(k0 + kk) * N + col0 + nq * 4);
            *(float4*)&Bs[kk][nq * 4] = v;
        }
        __syncthreads();
        #pragma unroll
        for (int kk = 0; kk < 16; kk++) {
            float4 b4 = *(float4*)&Bs[kk][tx * 4];
            float4 a0 = *(float4*)&As[kk][ty * 8];
            float4 a1 = *(float4*)&As[kk][ty * 8 + 4];
            float ar[8] = {a0.x, a0.y, a0.z, a0.w, a1.x, a1.y, a1.z, a1.w};
            float bc[4] = {b4.x, b4.y, b4.z, b4.w};
            #pragma unroll
            for (int r = 0; r < 8; r++)
                #pragma unroll
                for (int cc = 0; cc < 4; cc++)
                    acc[r][cc] = fmaf(ar[r], bc[cc], acc[r][cc]);
        }
        __syncthreads();
    }

    float bv[4] = {0.f, 0.f, 0.f, 0.f};
    if (bias) {
        #pragma unroll
        for (int cc = 0; cc < 4; cc++) bv[cc] = bias[col0 + tx * 4 + cc];
    }
    #pragma unroll
    for (int r = 0; r < 8; r++) {
        int rr = row0 + ty * 8 + r;
        float* cr;
        if constexpr (MODE == 3)
            cr = C + (size_t)(rr & 31) * (T_SZ * O_DIM) + (size_t)(rr >> 5) * O_DIM;
        else
            cr = C + (size_t)rr * N;
        float4 v;
        v.x = acc[r][0] + bv[0]; v.y = acc[r][1] + bv[1];
        v.z = acc[r][2] + bv[2]; v.w = acc[r][3] + bv[3];
        *(float4*)(cr + col0 + tx * 4) = v;
    }
}

// ---------------------------------------------------------------------------
// 32x32 tiled transpose: out[c][r] = in[r][c]
// ---------------------------------------------------------------------------
__global__ void transpose_f32(const float* __restrict__ in, float* __restrict__ out,
                              int rows, int cols)
{
    __shared__ float t[32][33];
    int c0 = blockIdx.x * 32, r0 = blockIdx.y * 32;
    int x = threadIdx.x, y = threadIdx.y;   // 32 x 8
    #pragma unroll
    for (int i = y; i < 32; i += 8) t[i][x] = in[(size_t)(r0 + i) * cols + c0 + x];
    __syncthreads();
    #pragma unroll
    for (int i = y; i < 32; i += 8) out[(size_t)(c0 + i) * rows + r0 + x] = t[x][i];
}

// ---------------------------------------------------------------------------
// One LSTM step:  z = xg_t + h_prev @ RR ; gates ; c,h update.
// Grid: 256 blocks (128 j-tiles x 2 b-halves), 256 threads.
// Thread: half = tid&1 (K split), jl = (tid>>1)&7, bl = tid>>4.
// Each (b,j) pair -> 2 threads over k-halves, 4 gate accumulators each,
// combined via shfl_xor; half==0 lane applies gates and writes c,h.
// ---------------------------------------------------------------------------
__global__ __launch_bounds__(256)
void lstm_step(const float* __restrict__ xg_t, const float* __restrict__ RRt,
               const float* __restrict__ h_prev, float* __restrict__ h_out,
               float* __restrict__ c_st, const float* __restrict__ p)
{
    __shared__ float h_lds[16 * 1028];   // 16 b-rows, stride 1028 (bank-conflict pad)
    const int tid = threadIdx.x;
    const int bh = blockIdx.x & 1;
    const int j0 = (blockIdx.x >> 1) * 8;

    // stage h_prev rows [bh*16, bh*16+16) into LDS (64KB), coalesced float4
    {
        const float4* src = (const float4*)(h_prev + bh * 16 * 1024);
        #pragma unroll
        for (int i = 0; i < 16; i++) {
            float4 v = src[i * 256 + tid];
            *(float4*)(h_lds + i * 1028 + tid * 4) = v;
        }
    }
    __syncthreads();

    const int half = tid & 1;
    const int jl   = (tid >> 1) & 7;
    const int bl   = tid >> 4;
    const int j    = j0 + jl;
    const int b    = bh * 16 + bl;

    const float* hrow = h_lds + bl * 1028 + half * 512;
    const float* r0 = RRt + (size_t)(0 * 1024 + j) * 1024 + half * 512;
    const float* r1 = RRt + (size_t)(1 * 1024 + j) * 1024 + half * 512;
    const float* r2 = RRt + (size_t)(2 * 1024 + j) * 1024 + half * 512;
    const float* r3 = RRt + (size_t)(3 * 1024 + j) * 1024 + half * 512;

    float a0 = 0.f, a1 = 0.f, a2 = 0.f, a3 = 0.f;
    #pragma unroll 4
    for (int k = 0; k < 512; k += 4) {
        float4 h4 = *(const float4*)(hrow + k);
        float4 v0 = *(const float4*)(r0 + k);
        float4 v1 = *(const float4*)(r1 + k);
        float4 v2 = *(const float4*)(r2 + k);
        float4 v3 = *(const float4*)(r3 + k);
        a0 += h4.x*v0.x + h4.y*v0.y + h4.z*v0.z + h4.w*v0.w;
        a1 += h4.x*v1.x + h4.y*v1.y + h4.z*v1.z + h4.w*v1.w;
        a2 += h4.x*v2.x + h4.y*v2.y + h4.z*v2.z + h4.w*v2.w;
        a3 += h4.x*v3.x + h4.y*v3.y + h4.z*v3.z + h4.w*v3.w;
    }
    // combine k-halves (partner lane = tid^1, same (b,j))
    a0 += __shfl_xor(a0, 1);
    a1 += __shfl_xor(a1, 1);
    a2 += __shfl_xor(a2, 1);
    a3 += __shfl_xor(a3, 1);

    if (half == 0) {
        float zi = xg_t[(size_t)b * G4 + 0 * 1024 + j] + a0;
        float zf = xg_t[(size_t)b * G4 + 1 * 1024 + j] + a1;
        float zg = xg_t[(size_t)b * G4 + 2 * 1024 + j] + a2;
        float zo = xg_t[(size_t)b * G4 + 3 * 1024 + j] + a3;
        float cv = c_st[b * 1024 + j];
        float ig = sigmf(zi + cv * p[j]);
        float fg = sigmf(zf + cv * p[1024 + j]);
        float gg = tanhfast(zg);
        float cn = fg * cv + ig * gg;
        float og = sigmf(zo + cn * p[2048 + j]);
        float hv = og * tanhfast(cn);
        c_st[b * 1024 + j]  = cn;
        h_out[b * 1024 + j] = hv;
    }
}

// ---------------------------------------------------------------------------
extern "C" void kernel_launch(void* const* d_in, const int* in_sizes, int n_in,
                              void* d_out, int out_size, void* d_ws, size_t ws_size,
                              hipStream_t stream)
{
    const float* inp    = (const float*)d_in[0];  // (32,512,256)
    const float* W      = (const float*)d_in[1];  // (256,4096)
    const float* R      = (const float*)d_in[2];  // (512,4096)
    const float* W_proj = (const float*)d_in[3];  // (1024,512)
    const float* p      = (const float*)d_in[4];  // (3072,)
    const float* bvec   = (const float*)d_in[5];  // (4096,)
    const float* lin_w  = (const float*)d_in[6];  // (256,512)
    const float* lin_b  = (const float*)d_in[7];  // (256,)
    float* out = (float*)d_out;
    char* ws = (char*)d_ws;

    float* RRbuf = (float*)(ws + 0);
    float* RRt   = (float*)(ws + 16777216);
    float* lwt   = (float*)(ws + 33554432);
    float* c_st  = (float*)(ws + 34078720);
    float* h_seq = (float*)(ws + 34209792);      // 513 slots of 32*1024
    float* xg_c  = (float*)(ws + 101449728);     // 64-step chunk
    float* hp_sq = (float*)(ws + 135004160);
    // requires ws_size >= 168558592 bytes

    // zero initial state (h_{-1} slot and c)
    hipMemsetAsync(h_seq, 0, B_SZ * H_DIM * sizeof(float), stream);
    hipMemsetAsync(c_st,  0, B_SZ * H_DIM * sizeof(float), stream);

    // RR = W_proj @ R   (1024 x 4096, K=512), then transpose -> RRt[g][k]
    gemm_f32<0><<<dim3(G4 / 64, H_DIM / 128), 256, 0, stream>>>(
        W_proj, R, nullptr, RRbuf, H_DIM, G4, P_DIM, 0);
    transpose_f32<<<dim3(G4 / 32, H_DIM / 32), dim3(32, 8), 0, stream>>>(
        RRbuf, RRt, H_DIM, G4);
    // lwt[p][o] = lin_w[o][p]
    transpose_f32<<<dim3(P_DIM / 32, O_DIM / 32), dim3(32, 8), 0, stream>>>(
        lin_w, lwt, O_DIM, P_DIM);

    // recurrence in 8 chunks of 64 steps; xg chunk precomputed per chunk
    for (int chunk = 0; chunk < 8; chunk++) {
        int t0 = chunk * 64;
        // xg[t0..t0+64) : M = 64*32 rows, N=4096, K=256, bias=b
        gemm_f32<1><<<dim3(G4 / 64, 2048 / 128), 256, 0, stream>>>(
            inp, W, bvec, xg_c, 2048, G4, I_DIM, t0);
        for (int tl = 0; tl < 64; tl++) {
            int t = t0 + tl;
            lstm_step<<<256, 256, 0, stream>>>(
                xg_c + (size_t)tl * B_SZ * G4, RRt,
                h_seq + (size_t)t * (B_SZ * H_DIM),
                h_seq + (size_t)(t + 1) * (B_SZ * H_DIM),
                c_st, p);
        }
    }

    // hp_seq[t][b][:] = h_seq[t+1][b][:] @ W_proj   (M=16384, N=512, K=1024)
    gemm_f32<2><<<dim3(P_DIM / 64, 16384 / 128), 256, 0, stream>>>(
        h_seq + B_SZ * H_DIM, W_proj, nullptr, hp_sq, 16384, P_DIM, H_DIM, 0);

    // out[b][t][:] = hp_seq[t][b][:] @ lwt + lin_b  (M=16384, N=256, K=512)
    gemm_f32<3><<<dim3(O_DIM / 64, 16384 / 128), 256, 0, stream>>>(
        hp_sq, lwt, lin_b, out, 16384, O_DIM, P_DIM, 0);
}

// Round 2
// 3393.644 us; speedup vs baseline: 10.6326x; 10.6326x over previous
//
#include <hip/hip_runtime.h>
#include <math.h>

// Problem dims
#define B_SZ   32
#define T_SZ   512
#define I_DIM  256
#define H_DIM  1024
#define P_DIM  512
#define G4     4096   // 4*H
#define O_DIM  256

typedef short short8 __attribute__((ext_vector_type(8)));
typedef float f32x4  __attribute__((ext_vector_type(4)));

__device__ __forceinline__ float sigmf(float x) { return 1.0f / (1.0f + __expf(-x)); }
__device__ __forceinline__ float tanhfast(float x) { return 1.0f - 2.0f / (__expf(2.0f * x) + 1.0f); }
__device__ __forceinline__ short f2bf(float f) {
    union { float f; unsigned u; } v; v.f = f;
    unsigned r = (v.u + 0x7FFF + ((v.u >> 16) & 1)) >> 16;
    return (short)r;
}

// ---------------------------------------------------------------------------
// Generic tiled f32 GEMM: C[M][N] = A[M][K] @ B[K][N] (+bias)
// BM=128, BN=64, BK=16, 256 threads, thread tile 8x4.
// MODE 0: RR = W_proj @ R                   (plain rows)
// MODE 1: xg chunk: A row r -> inputs[(r&31)*512 + t0 + (r>>5)] (row-major in i)
// MODE 2: hp_seq = h_seq @ W_proj           (plain rows)
// MODE 3: out: C row r=(t*32+b) -> d_out[b][t][:]
// ---------------------------------------------------------------------------
template<int MODE>
__global__ __launch_bounds__(256)
void gemm_f32(const float* __restrict__ A, const float* __restrict__ B,
              const float* __restrict__ bias, float* __restrict__ C,
              int M, int N, int K, int t0)
{
    __shared__ float As[16][136];
    __shared__ float Bs[16][64];
    const int row0 = blockIdx.y * 128;
    const int col0 = blockIdx.x * 64;
    const int tid = threadIdx.x;
    const int tx = tid & 15, ty = tid >> 4;

    float acc[8][4];
    #pragma unroll
    for (int r = 0; r < 8; r++)
        #pragma unroll
        for (int cc = 0; cc < 4; cc++) acc[r][cc] = 0.0f;

    for (int k0 = 0; k0 < K; k0 += 16) {
        #pragma unroll
        for (int e = 0; e < 2; e++) {
            int f4 = tid * 2 + e;
            int m  = f4 >> 2;
            int kq = f4 & 3;
            const float* ar;
            int r = row0 + m;
            if constexpr (MODE == 1)
                ar = A + (size_t)((r & 31) * 512 + t0 + (r >> 5)) * 256;
            else
                ar = A + (size_t)r * K;
            float4 v = *(const float4*)(ar + k0 + kq * 4);
            As[kq*4+0][m] = v.x; As[kq*4+1][m] = v.y;
            As[kq*4+2][m] = v.z; As[kq*4+3][m] = v.w;
        }
        {
            int kk = tid >> 4, nq = tid & 15;
            float4 v = *(const float4*)(B + (size_t)(k0 + kk) * N + col0 + nq * 4);
            *(float4*)&Bs[kk][nq * 4] = v;
        }
        __syncthreads();
        #pragma unroll
        for (int kk = 0; kk < 16; kk++) {
            float4 b4 = *(float4*)&Bs[kk][tx * 4];
            float4 a0 = *(float4*)&As[kk][ty * 8];
            float4 a1 = *(float4*)&As[kk][ty * 8 + 4];
            float ar[8] = {a0.x, a0.y, a0.z, a0.w, a1.x, a1.y, a1.z, a1.w};
            float bc[4] = {b4.x, b4.y, b4.z, b4.w};
            #pragma unroll
            for (int r = 0; r < 8; r++)
                #pragma unroll
                for (int cc = 0; cc < 4; cc++)
                    acc[r][cc] = fmaf(ar[r], bc[cc], acc[r][cc]);
        }
        __syncthreads();
    }

    float bv[4] = {0.f, 0.f, 0.f, 0.f};
    if (bias) {
        #pragma unroll
        for (int cc = 0; cc < 4; cc++) bv[cc] = bias[col0 + tx * 4 + cc];
    }
    #pragma unroll
    for (int r = 0; r < 8; r++) {
        int rr = row0 + ty * 8 + r;
        float* cr;
        if constexpr (MODE == 3)
            cr = C + (size_t)(rr & 31) * (T_SZ * O_DIM) + (size_t)(rr >> 5) * O_DIM;
        else
            cr = C + (size_t)rr * N;
        float4 v;
        v.x = acc[r][0] + bv[0]; v.y = acc[r][1] + bv[1];
        v.z = acc[r][2] + bv[2]; v.w = acc[r][3] + bv[3];
        *(float4*)(cr + col0 + tx * 4) = v;
    }
}

// ---------------------------------------------------------------------------
// 32x32 tiled transpose: out[c][r] = in[r][c]
// ---------------------------------------------------------------------------
__global__ void transpose_f32(const float* __restrict__ in, float* __restrict__ out,
                              int rows, int cols)
{
    __shared__ float t[32][33];
    int c0 = blockIdx.x * 32, r0 = blockIdx.y * 32;
    int x = threadIdx.x, y = threadIdx.y;
    #pragma unroll
    for (int i = y; i < 32; i += 8) t[i][x] = in[(size_t)(r0 + i) * cols + c0 + x];
    __syncthreads();
    #pragma unroll
    for (int i = y; i < 32; i += 8) out[(size_t)(c0 + i) * rows + r0 + x] = t[x][i];
}

// ---------------------------------------------------------------------------
// Pack RR (f32 [1024 k][4096 gatecol]) into per-block MFMA B-fragment order:
// RRbp[blk 128][wn 2][kt 32][lane 64][i 8] bf16.
//   local gatecol nl = wn*16 + (lane&15); g = nl>>3; jl = nl&7
//   global col = g*1024 + blk*8 + jl ;  k = kt*32 + (lane>>4)*8 + i
// Same k-slot formula is used for h_pack, so any k-permutation ambiguity in
// the HW fragment layout cancels (both operands permuted identically).
// ---------------------------------------------------------------------------
__global__ __launch_bounds__(256)
void pack_rr(const float* __restrict__ RRf, short* __restrict__ RRbp)
{
    int idx = blockIdx.x * 256 + threadIdx.x;     // short8 slot, 0..524287
    int lane = idx & 63;
    int kt   = (idx >> 6) & 31;
    int wn   = (idx >> 11) & 1;
    int blk  = idx >> 12;
    int nl = wn * 16 + (lane & 15);
    int g = nl >> 3, jl = nl & 7;
    int col = g * 1024 + blk * 8 + jl;
    int kbase = kt * 32 + (lane >> 4) * 8;
    short8 v;
    #pragma unroll
    for (int i = 0; i < 8; i++)
        v[i] = f2bf(RRf[(size_t)(kbase + i) * G4 + col]);
    ((short8*)RRbp)[idx] = v;
}

// ---------------------------------------------------------------------------
// One LSTM step via MFMA. Grid: 128 blocks (8 j-cols each), 256 threads.
// z[32 b][32 gc] = h @ RR slice.  Wave w: (wm=w&1 -> batch half,
// wn=w>>1 -> gatecol half). K=1024 -> 32 MFMA (2 indep acc chains).
// A-frags from hp_in (fragment-packed bf16, 64KB), B-frags from RRbp.
// Epilogue: LDS gate exchange, c/h update, write h_seq (f32) and
// hp_out in A-fragment order for the next step.
// ---------------------------------------------------------------------------
__global__ __launch_bounds__(256)
void lstm_step_mfma(const float* __restrict__ xg_t,
                    const short* __restrict__ RRbp,
                    const short* __restrict__ hp_in,
                    short* __restrict__ hp_out,
                    float* __restrict__ h_seq_t,
                    float* __restrict__ c_st,
                    const float* __restrict__ p)
{
    __shared__ float zbuf[32][33];
    const int tid  = threadIdx.x;
    const int bid  = blockIdx.x;          // j0 = bid*8
    const int lane = tid & 63;
    const int w    = tid >> 6;
    const int wm   = w & 1;
    const int wn   = w >> 1;

    const short8* Ap = (const short8*)hp_in + (size_t)(wm * 32) * 64 + lane;
    const short8* Bp = (const short8*)RRbp + (size_t)((bid * 2 + wn) * 32) * 64 + lane;

    f32x4 acc0 = {0.f, 0.f, 0.f, 0.f};
    f32x4 acc1 = {0.f, 0.f, 0.f, 0.f};
    #pragma unroll 8
    for (int kt = 0; kt < 32; kt += 2) {
        short8 a0 = Ap[(size_t)kt * 64];
        short8 b0 = Bp[(size_t)kt * 64];
        short8 a1 = Ap[(size_t)(kt + 1) * 64];
        short8 b1 = Bp[(size_t)(kt + 1) * 64];
        acc0 = __builtin_amdgcn_mfma_f32_16x16x32_bf16(a0, b0, acc0, 0, 0, 0);
        acc1 = __builtin_amdgcn_mfma_f32_16x16x32_bf16(a1, b1, acc1, 0, 0, 0);
    }
    acc0[0] += acc1[0]; acc0[1] += acc1[1]; acc0[2] += acc1[2]; acc0[3] += acc1[3];

    // C/D layout (HW-verified): col = lane&15, row = (lane>>4)*4 + r
    {
        int col = lane & 15;
        int row = (lane >> 4) * 4;
        #pragma unroll
        for (int r = 0; r < 4; r++)
            zbuf[wm * 16 + row + r][wn * 16 + col] = acc0[r];
    }
    __syncthreads();

    // epilogue: one thread per (b, jl)
    {
        int b = tid >> 3, jl = tid & 7;
        int j = bid * 8 + jl;
        float zi = zbuf[b][jl]      + xg_t[(size_t)b * G4 + j];
        float zf = zbuf[b][8 + jl]  + xg_t[(size_t)b * G4 + 1024 + j];
        float zg = zbuf[b][16 + jl] + xg_t[(size_t)b * G4 + 2048 + j];
        float zo = zbuf[b][24 + jl] + xg_t[(size_t)b * G4 + 3072 + j];
        float cv = c_st[b * H_DIM + j];
        float ig = sigmf(zi + cv * p[j]);
        float fg = sigmf(zf + cv * p[1024 + j]);
        float gg = tanhfast(zg);
        float cn = fg * cv + ig * gg;
        float og = sigmf(zo + cn * p[2048 + j]);
        float hv = og * tanhfast(cn);
        c_st[b * H_DIM + j]    = cn;
        h_seq_t[b * H_DIM + j] = hv;
        // write h in A-fragment order for next step
        int lane2 = (b & 15) | (((j & 31) >> 3) << 4);
        int kt2   = j >> 5;
        int wm2   = b >> 4;
        hp_out[(size_t)(((wm2 * 32 + kt2) * 64 + lane2)) * 8 + (j & 7)] = f2bf(hv);
    }
}

// ---------------------------------------------------------------------------
extern "C" void kernel_launch(void* const* d_in, const int* in_sizes, int n_in,
                              void* d_out, int out_size, void* d_ws, size_t ws_size,
                              hipStream_t stream)
{
    const float* inp    = (const float*)d_in[0];  // (32,512,256)
    const float* W      = (const float*)d_in[1];  // (256,4096)
    const float* R      = (const float*)d_in[2];  // (512,4096)
    const float* W_proj = (const float*)d_in[3];  // (1024,512)
    const float* p      = (const float*)d_in[4];  // (3072,)
    const float* bvec   = (const float*)d_in[5];  // (4096,)
    const float* lin_w  = (const float*)d_in[6];  // (256,512)
    const float* lin_b  = (const float*)d_in[7];  // (256,)
    float* out = (float*)d_out;
    char* ws = (char*)d_ws;

    float* RRbuf = (float*)(ws + 0);              // 16 MB
    short* RRbp  = (short*)(ws + 16777216);       // 8 MB
    float* lwt   = (float*)(ws + 25165824);       // 512 KB
    float* c_st  = (float*)(ws + 25690112);       // 128 KB
    short* hpk0  = (short*)(ws + 25821184);       // 64 KB
    short* hpk1  = (short*)(ws + 25886720);       // 64 KB
    float* h_seq = (float*)(ws + 25952256);       // 64 MB (512 slots)
    float* xg_c  = (float*)(ws + 93061120);       // 32 MB (64-step chunk)
    float* hp_sq = (float*)(ws + 126615552);      // 32 MB
    // requires ws_size >= 160,169,984 bytes

    hipMemsetAsync(hpk0, 0, 65536, stream);
    hipMemsetAsync(c_st, 0, B_SZ * H_DIM * sizeof(float), stream);

    // RR = W_proj @ R  (1024 x 4096, K=512), then pack to MFMA B-fragments
    gemm_f32<0><<<dim3(G4 / 64, H_DIM / 128), 256, 0, stream>>>(
        W_proj, R, nullptr, RRbuf, H_DIM, G4, P_DIM, 0);
    pack_rr<<<2048, 256, 0, stream>>>(RRbuf, RRbp);
    // lwt[p][o] = lin_w[o][p]
    transpose_f32<<<dim3(P_DIM / 32, O_DIM / 32), dim3(32, 8), 0, stream>>>(
        lin_w, lwt, O_DIM, P_DIM);

    // recurrence in 8 chunks of 64 steps; xg chunk precomputed per chunk
    for (int chunk = 0; chunk < 8; chunk++) {
        int t0 = chunk * 64;
        gemm_f32<1><<<dim3(G4 / 64, 2048 / 128), 256, 0, stream>>>(
            inp, W, bvec, xg_c, 2048, G4, I_DIM, t0);
        for (int tl = 0; tl < 64; tl++) {
            int t = t0 + tl;
            short* hin  = (t & 1) ? hpk1 : hpk0;
            short* hout = (t & 1) ? hpk0 : hpk1;
            lstm_step_mfma<<<128, 256, 0, stream>>>(
                xg_c + (size_t)tl * B_SZ * G4, RRbp, hin, hout,
                h_seq + (size_t)t * (B_SZ * H_DIM), c_st, p);
        }
    }

    // hp_seq[t][b][:] = h_seq[t][b][:] @ W_proj   (M=16384, N=512, K=1024)
    gemm_f32<2><<<dim3(P_DIM / 64, 16384 / 128), 256, 0, stream>>>(
        h_seq, W_proj, nullptr, hp_sq, 16384, P_DIM, H_DIM, 0);

    // out[b][t][:] = hp_seq[t][b][:] @ lwt + lin_b  (M=16384, N=256, K=512)
    gemm_f32<3><<<dim3(O_DIM / 64, 16384 / 128), 256, 0, stream>>>(
        hp_sq, lwt, lin_b, out, 16384, O_DIM, P_DIM, 0);
}

// Round 4
// 2851.452 us; speedup vs baseline: 12.6544x; 1.1901x over previous
//
#include <hip/hip_runtime.h>
#include <math.h>

// Problem dims
#define B_SZ   32
#define T_SZ   512
#define I_DIM  256
#define H_DIM  1024
#define P_DIM  512
#define G4     4096   // 4*H
#define O_DIM  256

typedef short short8 __attribute__((ext_vector_type(8)));
typedef float f32x4  __attribute__((ext_vector_type(4)));

__device__ __forceinline__ float sigmf(float x) { return 1.0f / (1.0f + __expf(-x)); }
__device__ __forceinline__ float tanhfast(float x) { return 1.0f - 2.0f / (__expf(2.0f * x) + 1.0f); }
__device__ __forceinline__ short f2bf(float f) {
    union { float f; unsigned u; } v; v.f = f;
    unsigned r = (v.u + 0x7FFF + ((v.u >> 16) & 1)) >> 16;
    return (short)r;
}
__device__ __forceinline__ float bf2f(short h) {
    union { unsigned u; float f; } v; v.u = ((unsigned)(unsigned short)h) << 16;
    return v.f;
}

// ---------------------------------------------------------------------------
// Elementwise f32 -> bf16 hi (+ optional lo residual) planes.
// ---------------------------------------------------------------------------
__global__ void split_copy(const float* __restrict__ in, short* __restrict__ hi,
                           short* __restrict__ lo, int n)
{
    int i = blockIdx.x * 256 + threadIdx.x;
    if (i < n) {
        float v = in[i];
        short h = f2bf(v);
        hi[i] = h;
        if (lo) lo[i] = f2bf(v - bf2f(h));
    }
}

// ---------------------------------------------------------------------------
// Transpose f32 [rows][cols] -> bf16 hi (+lo) [cols][rows].
// ---------------------------------------------------------------------------
__global__ void transpose_split(const float* __restrict__ in, short* __restrict__ hi,
                                short* __restrict__ lo, int rows, int cols)
{
    __shared__ float t[32][33];
    int c0 = blockIdx.x * 32, r0 = blockIdx.y * 32;
    int x = threadIdx.x, y = threadIdx.y;   // 32 x 8
    #pragma unroll
    for (int i = y; i < 32; i += 8) t[i][x] = in[(size_t)(r0 + i) * cols + c0 + x];
    __syncthreads();
    #pragma unroll
    for (int i = y; i < 32; i += 8) {
        float v = t[x][i];
        short h = f2bf(v);
        size_t o = (size_t)(c0 + i) * rows + r0 + x;
        hi[o] = h;
        if (lo) lo[o] = f2bf(v - bf2f(h));
    }
}

// ---------------------------------------------------------------------------
// MFMA bf16 GEMM body: C[M][N] = A[M][K] @ B[K][N] (+bias), B given
// TRANSPOSED as B^T[N][K] bf16 planes. A given as bf16 planes [M][K].
// 128x128 block tile, 4 waves (2x2) of 64x64, BK=64.
// SPLIT: 3-pass hi/lo (Ah*Bh + Ah*Bl + Al*Bh) ~ f32 precision.
// AMODE 0: A row r -> r ; 1: xg remap r -> (r&31)*512 + t0 + (r>>5), stride 256
// CMODE 0: f32 [M][N] ; 1: bf16 [M][N] ; 2: f32 out-remap row(t*32+b)->[b][t][:]
// LDS: XOR-swizzled slots (slot ^= row&7), pre-swizzled global source since
// global_load_lds writes linearly (both-sides-or-neither rule).
// NOTE: body is a __device__ template; the __global__ entry points are
// concrete (non-template) wrappers — hipcc failed to emit device stubs for
// template kernels of this shape (round-3 dlopen failure).
// ---------------------------------------------------------------------------
template<int SPLIT, int AMODE, int CMODE, int BIAS>
__device__ __forceinline__
void gemm_body(const short* __restrict__ Ah, const short* __restrict__ Al,
               const short* __restrict__ Bh, const short* __restrict__ Bl,
               const float* __restrict__ bias, void* __restrict__ Cp,
               int M, int N, int K, int t0)
{
    __shared__ short As[SPLIT + 1][8192];   // [plane][row*64 + k], 16KB each
    __shared__ short Bs[SPLIT + 1][8192];
    const int tid = threadIdx.x;
    const int l   = tid & 63;
    const int w   = tid >> 6;
    const int wm  = w & 1, wn = w >> 1;
    const int m0  = blockIdx.y * 128, n0 = blockIdx.x * 128;

    f32x4 acc[4][4] = {};

    for (int k0 = 0; k0 < K; k0 += 64) {
        __syncthreads();
        // ---- stage 128x64 A and B tiles (per plane 16KB, 4 issues/wave) ----
        #pragma unroll
        for (int q = 0; q < 4; q++) {
            int rg   = q * 4 + w;                 // 16 row-groups of 8 rows
            int rr   = (rg << 3) + (l >> 3);      // tile row 0..127
            int slot = (l & 7) ^ (rr & 7);        // pre-swizzled source slot
            int lidx = rg * 512 + l * 8;          // linear LDS dest (shorts)
            size_t aoff, boff;
            int ra = m0 + rr, rb = n0 + rr;
            if constexpr (AMODE == 1)
                aoff = (size_t)((ra & 31) * 512 + t0 + (ra >> 5)) * 256 + k0 + slot * 8;
            else
                aoff = (size_t)ra * K + k0 + slot * 8;
            boff = (size_t)rb * K + k0 + slot * 8;
            __builtin_amdgcn_global_load_lds(Ah + aoff, &As[0][lidx], 16, 0, 0);
            __builtin_amdgcn_global_load_lds(Bh + boff, &Bs[0][lidx], 16, 0, 0);
            if constexpr (SPLIT) {
                __builtin_amdgcn_global_load_lds(Al + aoff, &As[1][lidx], 16, 0, 0);
                __builtin_amdgcn_global_load_lds(Bl + boff, &Bs[1][lidx], 16, 0, 0);
            }
        }
        __syncthreads();

        // ---- fragments + MFMA ----
        #pragma unroll
        for (int ks = 0; ks < 2; ks++) {
            const int cb = (((ks * 4) + (l >> 4)) ^ (l & 7)) * 16;  // swizzled col byte
            short8 af[4], bfr[4], afl[4], bfl[4];
            #pragma unroll
            for (int mf = 0; mf < 4; mf++) {
                int mloc = wm * 64 + mf * 16 + (l & 15);
                af[mf] = *(const short8*)((const char*)As[0] + mloc * 128 + cb);
                if constexpr (SPLIT)
                    afl[mf] = *(const short8*)((const char*)As[1] + mloc * 128 + cb);
            }
            #pragma unroll
            for (int nf = 0; nf < 4; nf++) {
                int nloc = wn * 64 + nf * 16 + (l & 15);
                bfr[nf] = *(const short8*)((const char*)Bs[0] + nloc * 128 + cb);
                if constexpr (SPLIT)
                    bfl[nf] = *(const short8*)((const char*)Bs[1] + nloc * 128 + cb);
            }
            #pragma unroll
            for (int mf = 0; mf < 4; mf++)
                #pragma unroll
                for (int nf = 0; nf < 4; nf++)
                    acc[mf][nf] = __builtin_amdgcn_mfma_f32_16x16x32_bf16(
                        af[mf], bfr[nf], acc[mf][nf], 0, 0, 0);
            if constexpr (SPLIT) {
                #pragma unroll
                for (int mf = 0; mf < 4; mf++)
                    #pragma unroll
                    for (int nf = 0; nf < 4; nf++)
                        acc[mf][nf] = __builtin_amdgcn_mfma_f32_16x16x32_bf16(
                            af[mf], bfl[nf], acc[mf][nf], 0, 0, 0);
                #pragma unroll
                for (int mf = 0; mf < 4; mf++)
                    #pragma unroll
                    for (int nf = 0; nf < 4; nf++)
                        acc[mf][nf] = __builtin_amdgcn_mfma_f32_16x16x32_bf16(
                            afl[mf], bfr[nf], acc[mf][nf], 0, 0, 0);
            }
        }
    }

    // ---- epilogue: C/D layout col=lane&15, row=(lane>>4)*4+r ----
    float bv[4];
    if constexpr (BIAS) {
        #pragma unroll
        for (int nf = 0; nf < 4; nf++)
            bv[nf] = bias[n0 + wn * 64 + nf * 16 + (l & 15)];
    }
    #pragma unroll
    for (int mf = 0; mf < 4; mf++) {
        #pragma unroll
        for (int r = 0; r < 4; r++) {
            int row = m0 + wm * 64 + mf * 16 + (l >> 4) * 4 + r;
            #pragma unroll
            for (int nf = 0; nf < 4; nf++) {
                int col = n0 + wn * 64 + nf * 16 + (l & 15);
                float v = acc[mf][nf][r];
                if constexpr (BIAS) v += bv[nf];
                if constexpr (CMODE == 0)
                    ((float*)Cp)[(size_t)row * N + col] = v;
                else if constexpr (CMODE == 1)
                    ((short*)Cp)[(size_t)row * N + col] = f2bf(v);
                else
                    ((float*)Cp)[(size_t)(row & 31) * (T_SZ * O_DIM)
                                 + (size_t)(row >> 5) * O_DIM + col] = v;
            }
        }
    }
}

// ---- concrete (non-template) kernel entry points ----
__global__ __launch_bounds__(256)
void gemm_rr(const short* Ah, const short* Al, const short* Bh, const short* Bl,
             const float* bias, void* Cp, int M, int N, int K, int t0)
{ gemm_body<1, 0, 0, 0>(Ah, Al, Bh, Bl, bias, Cp, M, N, K, t0); }

__global__ __launch_bounds__(256)
void gemm_xg(const short* Ah, const short* Al, const short* Bh, const short* Bl,
             const float* bias, void* Cp, int M, int N, int K, int t0)
{ gemm_body<1, 1, 0, 1>(Ah, Al, Bh, Bl, bias, Cp, M, N, K, t0); }

__global__ __launch_bounds__(256)
void gemm_proj(const short* Ah, const short* Al, const short* Bh, const short* Bl,
               const float* bias, void* Cp, int M, int N, int K, int t0)
{ gemm_body<0, 0, 1, 0>(Ah, Al, Bh, Bl, bias, Cp, M, N, K, t0); }

__global__ __launch_bounds__(256)
void gemm_out(const short* Ah, const short* Al, const short* Bh, const short* Bl,
              const float* bias, void* Cp, int M, int N, int K, int t0)
{ gemm_body<0, 0, 2, 1>(Ah, Al, Bh, Bl, bias, Cp, M, N, K, t0); }

// ---------------------------------------------------------------------------
// Pack RR (f32 [1024 k][4096 gatecol]) into per-block MFMA B-fragment order
// (same as round 2; k-slot formula matches hp_out packing so permutation
// ambiguity cancels).
// ---------------------------------------------------------------------------
__global__ __launch_bounds__(256)
void pack_rr(const float* __restrict__ RRf, short* __restrict__ RRbp)
{
    int idx = blockIdx.x * 256 + threadIdx.x;     // short8 slot, 0..524287
    int lane = idx & 63;
    int kt   = (idx >> 6) & 31;
    int wn   = (idx >> 11) & 1;
    int blk  = idx >> 12;
    int nl = wn * 16 + (lane & 15);
    int g = nl >> 3, jl = nl & 7;
    int col = g * 1024 + blk * 8 + jl;
    int kbase = kt * 32 + (lane >> 4) * 8;
    short8 v;
    #pragma unroll
    for (int i = 0; i < 8; i++)
        v[i] = f2bf(RRf[(size_t)(kbase + i) * G4 + col]);
    ((short8*)RRbp)[idx] = v;
}

// ---------------------------------------------------------------------------
// One LSTM step via MFMA. Grid: 128 blocks (8 j-cols each), 256 threads.
// ---------------------------------------------------------------------------
__global__ __launch_bounds__(256)
void lstm_step_mfma(const float* __restrict__ xg_t,
                    const short* __restrict__ RRbp,
                    const short* __restrict__ hp_in,
                    short* __restrict__ hp_out,
                    short* __restrict__ h_bf_t,
                    float* __restrict__ c_st,
                    const float* __restrict__ p)
{
    __shared__ float zbuf[32][33];
    const int tid  = threadIdx.x;
    const int bid  = blockIdx.x;          // j0 = bid*8
    const int lane = tid & 63;
    const int w    = tid >> 6;
    const int wm   = w & 1;
    const int wn   = w >> 1;

    const short8* Ap = (const short8*)hp_in + (size_t)(wm * 32) * 64 + lane;
    const short8* Bp = (const short8*)RRbp + (size_t)((bid * 2 + wn) * 32) * 64 + lane;

    f32x4 acc0 = {0.f, 0.f, 0.f, 0.f};
    f32x4 acc1 = {0.f, 0.f, 0.f, 0.f};
    #pragma unroll 8
    for (int kt = 0; kt < 32; kt += 2) {
        short8 a0 = Ap[(size_t)kt * 64];
        short8 b0 = Bp[(size_t)kt * 64];
        short8 a1 = Ap[(size_t)(kt + 1) * 64];
        short8 b1 = Bp[(size_t)(kt + 1) * 64];
        acc0 = __builtin_amdgcn_mfma_f32_16x16x32_bf16(a0, b0, acc0, 0, 0, 0);
        acc1 = __builtin_amdgcn_mfma_f32_16x16x32_bf16(a1, b1, acc1, 0, 0, 0);
    }
    acc0[0] += acc1[0]; acc0[1] += acc1[1]; acc0[2] += acc1[2]; acc0[3] += acc1[3];

    {
        int col = lane & 15;
        int row = (lane >> 4) * 4;
        #pragma unroll
        for (int r = 0; r < 4; r++)
            zbuf[wm * 16 + row + r][wn * 16 + col] = acc0[r];
    }
    __syncthreads();

    {
        int b = tid >> 3, jl = tid & 7;
        int j = bid * 8 + jl;
        float zi = zbuf[b][jl]      + xg_t[(size_t)b * G4 + j];
        float zf = zbuf[b][8 + jl]  + xg_t[(size_t)b * G4 + 1024 + j];
        float zg = zbuf[b][16 + jl] + xg_t[(size_t)b * G4 + 2048 + j];
        float zo = zbuf[b][24 + jl] + xg_t[(size_t)b * G4 + 3072 + j];
        float cv = c_st[b * H_DIM + j];
        float ig = sigmf(zi + cv * p[j]);
        float fg = sigmf(zf + cv * p[1024 + j]);
        float gg = tanhfast(zg);
        float cn = fg * cv + ig * gg;
        float og = sigmf(zo + cn * p[2048 + j]);
        float hv = og * tanhfast(cn);
        c_st[b * H_DIM + j]   = cn;
        h_bf_t[b * H_DIM + j] = f2bf(hv);
        // write h in A-fragment order for next step
        int lane2 = (b & 15) | (((j & 31) >> 3) << 4);
        int kt2   = j >> 5;
        int wm2   = b >> 4;
        hp_out[(size_t)(((wm2 * 32 + kt2) * 64 + lane2)) * 8 + (j & 7)] = f2bf(hv);
    }
}

// ---------------------------------------------------------------------------
extern "C" void kernel_launch(void* const* d_in, const int* in_sizes, int n_in,
                              void* d_out, int out_size, void* d_ws, size_t ws_size,
                              hipStream_t stream)
{
    const float* inp    = (const float*)d_in[0];  // (32,512,256)
    const float* W      = (const float*)d_in[1];  // (256,4096)
    const float* R      = (const float*)d_in[2];  // (512,4096)
    const float* W_proj = (const float*)d_in[3];  // (1024,512)
    const float* p      = (const float*)d_in[4];  // (3072,)
    const float* bvec   = (const float*)d_in[5];  // (4096,)
    const float* lin_w  = (const float*)d_in[6];  // (256,512)
    const float* lin_b  = (const float*)d_in[7];  // (256,)
    float* out = (float*)d_out;
    char* ws = (char*)d_ws;

    float* RRbuf = (float*)(ws + 0);              // 16 MB
    short* RRbp  = (short*)(ws + 16777216);       // 8 MB
    short* Wp_hi = (short*)(ws + 25165824);       // 1 MB  (W_proj planes, row-major)
    short* Wp_lo = (short*)(ws + 26214400);
    short* Rt_hi = (short*)(ws + 27262976);       // 4 MB  (R^T planes [4096][512])
    short* Rt_lo = (short*)(ws + 31457280);
    short* Wt_hi = (short*)(ws + 35651584);       // 2 MB  (W^T planes [4096][256])
    short* Wt_lo = (short*)(ws + 37748736);
    short* in_hi = (short*)(ws + 39845888);       // 8 MB  (inputs planes, row-major)
    short* in_lo = (short*)(ws + 48234496);
    short* Wpt   = (short*)(ws + 56623104);       // 1 MB  (W_proj^T bf16 [512][1024])
    short* lwb   = (short*)(ws + 57671680);       // 256 KB (lin_w bf16 [256][512])
    float* c_st  = (float*)(ws + 57933824);       // 128 KB
    short* hpk0  = (short*)(ws + 58064896);       // 64 KB
    short* hpk1  = (short*)(ws + 58130432);       // 64 KB
    short* h_bf  = (short*)(ws + 58195968);       // 32 MB  ([512][32][1024] bf16)
    float* xg_c  = (float*)(ws + 91750400);       // 32 MB  (64-step chunk, f32)
    short* hp_bf = (short*)(ws + 125304832);      // 16 MB  ([16384][512] bf16)
    // requires ws_size >= 142,082,048 bytes

    hipMemsetAsync(hpk0, 0, 65536, stream);
    hipMemsetAsync(c_st, 0, B_SZ * H_DIM * sizeof(float), stream);

    // ---- prepack weights/inputs into bf16 (hi/lo) planes ----
    split_copy<<<(H_DIM * P_DIM + 255) / 256, 256, 0, stream>>>(W_proj, Wp_hi, Wp_lo, H_DIM * P_DIM);
    split_copy<<<(B_SZ * T_SZ * I_DIM + 255) / 256, 256, 0, stream>>>(inp, in_hi, in_lo, B_SZ * T_SZ * I_DIM);
    split_copy<<<(O_DIM * P_DIM + 255) / 256, 256, 0, stream>>>(lin_w, lwb, nullptr, O_DIM * P_DIM);
    transpose_split<<<dim3(G4 / 32, P_DIM / 32), dim3(32, 8), 0, stream>>>(R, Rt_hi, Rt_lo, P_DIM, G4);
    transpose_split<<<dim3(G4 / 32, I_DIM / 32), dim3(32, 8), 0, stream>>>(W, Wt_hi, Wt_lo, I_DIM, G4);
    transpose_split<<<dim3(P_DIM / 32, H_DIM / 32), dim3(32, 8), 0, stream>>>(W_proj, Wpt, nullptr, H_DIM, P_DIM);

    // ---- RR = W_proj @ R (split, ~f32 precision), pack to B-fragments ----
    gemm_rr<<<dim3(G4 / 128, H_DIM / 128), 256, 0, stream>>>(
        Wp_hi, Wp_lo, Rt_hi, Rt_lo, nullptr, RRbuf, H_DIM, G4, P_DIM, 0);
    pack_rr<<<2048, 256, 0, stream>>>(RRbuf, RRbp);

    // ---- recurrence in 8 chunks of 64 steps ----
    for (int chunk = 0; chunk < 8; chunk++) {
        int t0 = chunk * 64;
        // xg[t0..t0+64): M=2048 rows (tl*32+b), N=4096, K=256, split + bias
        gemm_xg<<<dim3(G4 / 128, 2048 / 128), 256, 0, stream>>>(
            in_hi, in_lo, Wt_hi, Wt_lo, bvec, xg_c, 2048, G4, I_DIM, t0);
        for (int tl = 0; tl < 64; tl++) {
            int t = t0 + tl;
            short* hin  = (t & 1) ? hpk1 : hpk0;
            short* hout = (t & 1) ? hpk0 : hpk1;
            lstm_step_mfma<<<128, 256, 0, stream>>>(
                xg_c + (size_t)tl * B_SZ * G4, RRbp, hin, hout,
                h_bf + (size_t)t * (B_SZ * H_DIM), c_st, p);
        }
    }

    // ---- hp = h @ W_proj (single-pass bf16, bf16 output) ----
    gemm_proj<<<dim3(P_DIM / 128, 16384 / 128), 256, 0, stream>>>(
        h_bf, nullptr, Wpt, nullptr, nullptr, hp_bf, 16384, P_DIM, H_DIM, 0);

    // ---- out = hp @ lin_w^T + lin_b (single-pass bf16, f32 remapped out) ----
    gemm_out<<<dim3(O_DIM / 128, 16384 / 128), 256, 0, stream>>>(
        hp_bf, nullptr, lwb, nullptr, lin_b, out, 16384, O_DIM, P_DIM, 0);
}